// Round 13
// baseline (213.204 us; speedup 1.0000x reference)
//
#include <hip/hip_runtime.h>
#include <hip/hip_bf16.h>
#include <stdint.h>

typedef int v4i __attribute__((ext_vector_type(4)));
typedef int v16i __attribute__((ext_vector_type(16)));

#define TOK 8192   // B*S
#define DIN 4096   // K (bytes per row, int8)
#define DOUT 4096  // N

#define NT 32      // K-tiles: 4096 / 128 bytes

// ---------------- Kernel 1: per-token dynamic quantization ----------------
__global__ __launch_bounds__(256) void quant_rows(const float* __restrict__ x,
                                                  int8_t* __restrict__ xq,
                                                  float* __restrict__ ascale) {
    const int row = blockIdx.x;
    const int t = threadIdx.x;
    const float* __restrict__ xr = x + (size_t)row * DIN;
    float4 v[4];
    float amax = 0.0f;
#pragma unroll
    for (int i = 0; i < 4; ++i) {
        v[i] = reinterpret_cast<const float4*>(xr)[t + 256 * i];
        amax = fmaxf(amax, fmaxf(fmaxf(fabsf(v[i].x), fabsf(v[i].y)),
                                 fmaxf(fabsf(v[i].z), fabsf(v[i].w))));
    }
#pragma unroll
    for (int off = 1; off < 64; off <<= 1)
        amax = fmaxf(amax, __shfl_xor(amax, off, 64));
    __shared__ float wmax[4];
    if ((t & 63) == 0) wmax[t >> 6] = amax;
    __syncthreads();
    amax = fmaxf(fmaxf(wmax[0], wmax[1]), fmaxf(wmax[2], wmax[3]));
    const float scale = fmaxf(amax, 1e-8f) / 127.0f;  // exact ref semantics
    if (t == 0) ascale[row] = scale;
    uint32_t* __restrict__ qr = reinterpret_cast<uint32_t*>(xq + (size_t)row * DIN);
#pragma unroll
    for (int i = 0; i < 4; ++i) {
        // IEEE div + rintf (half-even) == jnp.round(x / act_scale)
        int q0 = (int)fminf(fmaxf(rintf(v[i].x / scale), -128.0f), 127.0f);
        int q1 = (int)fminf(fmaxf(rintf(v[i].y / scale), -128.0f), 127.0f);
        int q2 = (int)fminf(fmaxf(rintf(v[i].z / scale), -128.0f), 127.0f);
        int q3 = (int)fminf(fmaxf(rintf(v[i].w / scale), -128.0f), 127.0f);
        qr[t + 256 * i] = (uint32_t)((q0 & 0xFF) | ((q1 & 0xFF) << 8) |
                                     ((q2 & 0xFF) << 16) | ((q3 & 0xFF) << 24));
    }
}

// ---------------- Kernel 2: weight repack int32 -> int8 ----------------
__global__ __launch_bounds__(256) void pack_w(const int* __restrict__ wq,
                                              uint32_t* __restrict__ w8) {
    const size_t i = (size_t)blockIdx.x * 256 + threadIdx.x;
    int4 a = reinterpret_cast<const int4*>(wq)[i];
    w8[i] = (uint32_t)((a.x & 0xFF) | ((a.y & 0xFF) << 8) |
                       ((a.z & 0xFF) << 16) | ((a.w & 0xFF) << 24));
}

// ---------------- Kernel 3: int8 GEMM, 128x128 tile, 2 blocks/CU ----------
// R12's verified 8-phase schedule (stage order, VM(4) certs, pre/window read
// split, LGKM0 points all byte-identical), with the MFMA shape swapped to
// mfma_i32_32x32x32_i8 (4404 TOPS ubench vs 3944 for 16x16x64; half the
// issue slots). Per wave: 64x64 output = 2x2 frags of 32x32, 16 acc regs
// each. Operand layout: row/col = l&31, k-chunk h = l>>5; swizzle slot =
// (2*kc+h)^(l&7) (r&7 == l&7 still holds). C/D: col=lane&31,
// row=(reg&3)+8*(reg>>2)+4*(lane>>5) (m74/m101, dtype-independent).
// Exact int32 accumulate, fused dequant epilogue.
__global__ __launch_bounds__(256, 2) void gemm_i8(const int8_t* __restrict__ A,
                                                  const int8_t* __restrict__ B,
                                                  const float* __restrict__ ascale,
                                                  const float* __restrict__ wscale,
                                                  const float* __restrict__ bias,
                                                  float* __restrict__ C) {
    __shared__ __attribute__((aligned(16))) uint8_t lds[65536];  // A:[0,32K) B:[32K,64K)
    const int tid = threadIdx.x;
    const int bn = blockIdx.x, bm = blockIdx.y;

    // ---- staging precompute (inverse-swizzled global source, linear dest)
    const int srow = tid >> 3;  // row 0..31 within a 32-row load group
    const int sp = tid & 7;     // 16B slot within 128B row
    const size_t soff0 = (size_t)srow * DIN + (size_t)(((sp ^ (srow & 7)) * 16));
    const size_t soff1 = soff0 + (size_t)32 * DIN;  // (srow+32)&7 == srow&7
    const uint32_t dst0 = (uint32_t)tid * 16u;
    const uint32_t dst1 = dst0 + 4096u;
    const int8_t* gA = A + (size_t)bm * 128 * DIN;
    const int8_t* gB = B + (size_t)bn * 128 * DIN;

    // STAGE_HALF: one 64-row half (8KB) of a 128x128B tile region = 2 loads.
#define STAGE_HALF(gmat, rbase, bufv, h, ktc)                                            \
    do {                                                                                 \
        const int8_t* _s = (gmat) + ((size_t)(h)*64 * DIN) + ((size_t)(ktc)*128);        \
        const uint32_t _d = (rbase) + (uint32_t)(bufv)*16384u + (uint32_t)(h)*8192u;     \
        __builtin_amdgcn_global_load_lds(                                                \
            (const __attribute__((address_space(1))) void*)(_s + soff0),                 \
            (__attribute__((address_space(3))) void*)(&lds[_d + dst0]), 16, 0, 0);       \
        __builtin_amdgcn_global_load_lds(                                                \
            (const __attribute__((address_space(1))) void*)(_s + soff1),                 \
            (__attribute__((address_space(3))) void*)(&lds[_d + dst1]), 16, 0, 0);       \
    } while (0)

    // ---- wave / lane geometry: 4 waves 2x2, each 64x64 output (2x2 of 32x32)
    const int wid = tid >> 6, l = tid & 63;
    const int wm = (wid >> 1) * 64;  // 2 M-waves
    const int wn = (wid & 1) * 64;   // 2 N-waves
    const int l31 = l & 31;          // fragment row (A) / col (B)
    const int h = l >> 5;            // 16B k-half within a 32B k-chunk
    const int c7 = l & 7;
    // swizzled k-slot offsets for the four K=32 sub-MFMAs of a 128B K-step
    const uint32_t aBase = (uint32_t)((wm + l31) * 128);
    const uint32_t bBase = (uint32_t)((wn + l31) * 128);
    const uint32_t aK0 = aBase + (uint32_t)(((0 + h) ^ c7) * 16);
    const uint32_t aK1 = aBase + (uint32_t)(((2 + h) ^ c7) * 16);
    const uint32_t aK2 = aBase + (uint32_t)(((4 + h) ^ c7) * 16);
    const uint32_t aK3 = aBase + (uint32_t)(((6 + h) ^ c7) * 16);
    const uint32_t bK0 = bBase + (uint32_t)(((0 + h) ^ c7) * 16);
    const uint32_t bK1 = bBase + (uint32_t)(((2 + h) ^ c7) * 16);
    const uint32_t bK2 = bBase + (uint32_t)(((4 + h) ^ c7) * 16);
    const uint32_t bK3 = bBase + (uint32_t)(((6 + h) ^ c7) * 16);
    // ds literal offsets: A: buf0 mi0="0" mi1="4096", buf1 "16384"/"20480";
    //                     B: +32768 -> "32768"/"36864", buf1 "49152"/"53248".

    v16i c00 = {0, 0, 0, 0, 0, 0, 0, 0, 0, 0, 0, 0, 0, 0, 0, 0};
    v16i c01 = {0, 0, 0, 0, 0, 0, 0, 0, 0, 0, 0, 0, 0, 0, 0, 0};
    v16i c10 = {0, 0, 0, 0, 0, 0, 0, 0, 0, 0, 0, 0, 0, 0, 0, 0};
    v16i c11 = {0, 0, 0, 0, 0, 0, 0, 0, 0, 0, 0, 0, 0, 0, 0, 0};

    v4i aF0[4], aF1[4], bF0[4], bF1[4];

#define DSR(d, b, o) asm volatile("ds_read_b128 %0, %1 offset:" o : "=v"(d) : "v"(b))

#define RD_AF0(o) do { DSR(aF0[0], aK0, o); DSR(aF0[1], aK1, o); DSR(aF0[2], aK2, o); DSR(aF0[3], aK3, o); } while (0)
#define RD_AF1(o) do { DSR(aF1[0], aK0, o); DSR(aF1[1], aK1, o); DSR(aF1[2], aK2, o); DSR(aF1[3], aK3, o); } while (0)
#define RD_BF0(o) do { DSR(bF0[0], bK0, o); DSR(bF0[1], bK1, o); DSR(bF0[2], bK2, o); DSR(bF0[3], bK3, o); } while (0)
#define RD_BF1(o) do { DSR(bF1[0], bK0, o); DSR(bF1[1], bK1, o); DSR(bF1[2], bK2, o); DSR(bF1[3], bK3, o); } while (0)

#define BAR() asm volatile("s_barrier" ::: "memory")
#define LGKM0()                                                \
    do {                                                       \
        asm volatile("s_waitcnt lgkmcnt(0)" ::: "memory");     \
        __builtin_amdgcn_sched_barrier(0);                     \
    } while (0)
#define PRIO1() __builtin_amdgcn_s_setprio(1)
#define PRIO0()                                \
    do {                                       \
        __builtin_amdgcn_sched_barrier(0);     \
        __builtin_amdgcn_s_setprio(0);         \
    } while (0)
#define VM(n) asm volatile("s_waitcnt vmcnt(" #n ")" ::: "memory")

    // 4 chained MFMAs over the K-step's 4 k-chunks (long instrs -> chain ok)
#define MFMA_Q(AF, BF, CC)                                                       \
    do {                                                                         \
        _Pragma("unroll") for (int kc = 0; kc < 4; ++kc) {                       \
            CC = __builtin_amdgcn_mfma_i32_32x32x32_i8(AF[kc], BF[kc], CC,       \
                                                       0, 0, 0);                 \
        }                                                                        \
    } while (0)

    // ---- prologue: stage kt0 (all 4 halves) + kt1 (A halves); cert kt0.
    // Loop invariant entering PH1: vm queue = [v.A(4)].
    STAGE_HALF(gA, 0u, 0, 0, 0);
    STAGE_HALF(gA, 0u, 0, 1, 0);
    STAGE_HALF(gB, 32768u, 0, 0, 0);
    STAGE_HALF(gB, 32768u, 0, 1, 0);
    STAGE_HALF(gA, 0u, 1, 0, 1);
    STAGE_HALF(gA, 0u, 1, 1, 1);
    VM(4);  // kt0's 8 loads drained; kt1.A (4) in flight

    // ---- main loop: u=2t (buf0, PH1-4), v=2t+1 (buf1, PH5-8)
    for (int t = 0; t < NT / 2; ++t) {
        const int cv = 2 * t + 1;
        const int cu2 = (2 * t + 2 < NT) ? 2 * t + 2 : NT - 1;  // clamp: dead stage
        const int cv2 = (2 * t + 3 < NT) ? 2 * t + 3 : NT - 1;

        // PH1: u.Q(0,0) | stage v.B0 -> buf1 | pre-read aF0,bF0 | window aF1,bF1
        BAR();
        STAGE_HALF(gB, 32768u, 1, 0, cv);
        RD_AF0("0"); RD_BF0("32768");
        LGKM0();
        PRIO1();
        RD_AF1("4096"); RD_BF1("36864");
        MFMA_Q(aF0, bF0, c00);
        PRIO0();

        // PH2: u.Q(0,1) | stage v.B1 -> buf1 | LGKM0 drains window reads
        BAR();
        STAGE_HALF(gB, 32768u, 1, 1, cv);
        LGKM0();
        PRIO1(); MFMA_Q(aF0, bF1, c01); PRIO0();

        // PH3: u.Q(1,0) | stage u'.A0 -> buf0 (aF reads drained PH2)
        BAR();
        STAGE_HALF(gA, 0u, 0, 0, cu2);
        LGKM0();
        PRIO1(); MFMA_Q(aF1, bF0, c10); PRIO0();

        // PH4: u.Q(1,1) | stage u'.A1 -> buf0 | VM(4): v fully landed
        BAR();
        STAGE_HALF(gA, 0u, 0, 1, cu2);
        LGKM0();
        PRIO1(); MFMA_Q(aF1, bF1, c11); PRIO0();
        VM(4);

        // PH5: v.Q(0,0) | stage u'.B0 -> buf0 | pre-read | window
        BAR();
        STAGE_HALF(gB, 32768u, 0, 0, cu2);
        RD_AF0("16384"); RD_BF0("49152");
        LGKM0();
        PRIO1();
        RD_AF1("20480"); RD_BF1("53248");
        MFMA_Q(aF0, bF0, c00);
        PRIO0();

        // PH6: v.Q(0,1) | stage u'.B1 -> buf0
        BAR();
        STAGE_HALF(gB, 32768u, 0, 1, cu2);
        LGKM0();
        PRIO1(); MFMA_Q(aF0, bF1, c01); PRIO0();

        // PH7: v.Q(1,0) | stage v'.A0 -> buf1 (buf1.A reads drained PH6)
        BAR();
        STAGE_HALF(gA, 0u, 1, 0, cv2);
        LGKM0();
        PRIO1(); MFMA_Q(aF1, bF0, c10); PRIO0();

        // PH8: v.Q(1,1) | stage v'.A1 -> buf1 | VM(4): u' fully landed
        BAR();
        STAGE_HALF(gA, 0u, 1, 1, cv2);
        LGKM0();
        PRIO1(); MFMA_Q(aF1, bF1, c11); PRIO0();
        VM(4);
    }

    // drain trailing reads and clamped prefetches
    asm volatile("s_waitcnt lgkmcnt(0)" ::: "memory");
    VM(0);

    // ---- epilogue: 32x32 C/D layout col=lane&31, row=(reg&3)+8*(reg>>2)+4*h
    const int colb = bn * 128 + wn + l31;
    const float ws0 = wscale[colb], ws1 = wscale[colb + 32];
    const float bb0 = bias[colb], bb1 = bias[colb + 32];
    const int rowb = bm * 128 + wm + 4 * h;
#pragma unroll
    for (int r = 0; r < 16; ++r) {
        const int ro = (r & 3) + 8 * (r >> 2);
        const int row0 = rowb + ro, row1 = row0 + 32;
        const float as0 = ascale[row0], as1 = ascale[row1];
        C[(size_t)row0 * DOUT + colb]      = (float)c00[r] * as0 * ws0 + bb0;
        C[(size_t)row0 * DOUT + colb + 32] = (float)c01[r] * as0 * ws1 + bb1;
        C[(size_t)row1 * DOUT + colb]      = (float)c10[r] * as1 * ws0 + bb0;
        C[(size_t)row1 * DOUT + colb + 32] = (float)c11[r] * as1 * ws1 + bb1;
    }
#undef STAGE_HALF
#undef DSR
#undef RD_AF0
#undef RD_AF1
#undef RD_BF0
#undef RD_BF1
#undef BAR
#undef LGKM0
#undef PRIO1
#undef PRIO0
#undef VM
#undef MFMA_Q
}

extern "C" void kernel_launch(void* const* d_in, const int* in_sizes, int n_in,
                              void* d_out, int out_size, void* d_ws, size_t ws_size,
                              hipStream_t stream) {
    const float* x = (const float*)d_in[0];
    const int* wq = (const int*)d_in[1];
    const float* wscale = (const float*)d_in[2];
    const float* bias = (const float*)d_in[3];
    float* out = (float*)d_out;

    // workspace: xq[TOK*DIN] i8 | w8[DOUT*DIN] i8 | ascale[TOK] f32
    int8_t* xq = (int8_t*)d_ws;
    int8_t* w8 = xq + (size_t)TOK * DIN;
    float* ascale = (float*)(w8 + (size_t)DOUT * DIN);

    quant_rows<<<TOK, 256, 0, stream>>>(x, xq, ascale);
    pack_w<<<(int)(((size_t)DOUT * DIN / 4) / 256), 256, 0, stream>>>(wq, (uint32_t*)w8);
    gemm_i8<<<dim3(DOUT / 128, TOK / 128), 256, 0, stream>>>(xq, w8, ascale, wscale, bias, out);
}